// Round 3
// baseline (223.215 us; speedup 1.0000x reference)
//
#include <hip/hip_runtime.h>

// SoftPerspectiveShader: barycentric texture sampling + softmax RGB blend.
// N=4, H=W=512, K=8, F=200000. One thread per pixel.
//
// R1: gate face_colors gather on weight magnitude (zbuf sorted ->
//     exp((zinv-zmax)/1e-4) underflows unless within ~1.2e-3 of zmax).
// R2/R3: nontemporal streams (face_colors stays cache-resident), deferred
//     bary, VGPR 28. Result: 65 us kernel, 2.8 TB/s, VALU 10%, occ 65%
//     -> latency-bound; traffic already near-minimal (168 MB fetch).
// R4 (this round): collapse the two serialized memory round-trips.
//     pix_to_face is randint(-1,F): valid w.p. ~1-5e-6, and zbuf is sorted,
//     so the winner (zmax attainer) is the FIRST VALID fragment -> its index
//     depends only on p2f. Cascade-select (kw, fid_w) from p2f alone and
//     issue the bary + color gather immediately after the p2f loads, while
//     zbuf/dists are still in flight. Extra gate-passers (~0.8%/pixel) go
//     through an execz-skipped fallback loop.

#define KFRAG 8

typedef int   ivec4 __attribute__((ext_vector_type(4)));
typedef float fvec4 __attribute__((ext_vector_type(4)));

__global__ __launch_bounds__(256) void soft_shader_kernel(
    const int*   __restrict__ p2f,         // [NP, 8]
    const float* __restrict__ bary,        // [NP, 8, 3]
    const float* __restrict__ zbuf,        // [NP, 8]
    const float* __restrict__ dists,       // [NP, 8]
    const float* __restrict__ face_colors, // [F, 3, 3]
    float*       __restrict__ out,         // [NP, 4]
    int NP)
{
    constexpr float SIGMA_INV = 1.0f / 1e-4f;
    constexpr float GAMMA_INV = 1.0f / 1e-4f;
    constexpr float EPS    = 1e-10f;
    constexpr float ZNEAR  = 1.0f;
    constexpr float ZFAR   = 100.0f;
    constexpr float ZSCALE = 1.0f / (ZFAR - ZNEAR);
    // exp((zinv-zmax)*1e4) < 1e-5 for zinv-zmax < -1.15e-3: contribution
    // far below the check threshold.
    constexpr float ZCUT = -1.2e-3f;

    int p = blockIdx.x * blockDim.x + threadIdx.x;
    if (p >= NP) return;

    // ---- p2f first: it is the root of the gather address chain ----
    const ivec4* p2f4 = (const ivec4*)p2f + (size_t)p * 2;
    ivec4 f0 = __builtin_nontemporal_load(p2f4 + 0);
    ivec4 f1 = __builtin_nontemporal_load(p2f4 + 1);

    // independent streams: issued now, consumed after the gather is launched
    const fvec4* zb4 = (const fvec4*)zbuf + (size_t)p * 2;
    fvec4 z0 = __builtin_nontemporal_load(zb4 + 0);
    fvec4 z1 = __builtin_nontemporal_load(zb4 + 1);
    const fvec4* dd4 = (const fvec4*)dists + (size_t)p * 2;
    fvec4 d0 = __builtin_nontemporal_load(dd4 + 0);
    fvec4 d1 = __builtin_nontemporal_load(dd4 + 1);

    int fid[KFRAG] = {f0.x, f0.y, f0.z, f0.w, f1.x, f1.y, f1.z, f1.w};

    // winner = first valid fragment (sorted zbuf -> largest zinv among valid)
    int fidw = -1, kw = 0;
#pragma unroll
    for (int k = KFRAG - 1; k >= 0; --k)
        if (fid[k] >= 0) { fidw = fid[k]; kw = k; }

    // ---- issue winner's bary + color gather as soon as p2f lands ----
    float wb0 = 0.f, wb1 = 0.f, wb2 = 0.f;
    float fcv[9] = {0,0,0,0,0,0,0,0,0};
    if (fidw >= 0) {
        const float* bp = bary + (size_t)p * (KFRAG * 3) + kw * 3;
        wb0 = bp[0]; wb1 = bp[1]; wb2 = bp[2];
        const float* fc = face_colors + (size_t)fidw * 9;
#pragma unroll
        for (int i = 0; i < 9; ++i) fcv[i] = fc[i];
    }

    // ---- gate math (consumes zbuf/dists; overlaps the gather round-trip) ----
    float zb_[KFRAG] = {z0.x, z0.y, z0.z, z0.w, z1.x, z1.y, z1.z, z1.w};
    float dd_[KFRAG] = {d0.x, d0.y, d0.z, d0.w, d1.x, d1.y, d1.z, d1.w};

    float zinv[KFRAG], prob[KFRAG];
    float zmax = EPS;
    float keep = 1.0f; // prod(1 - prob) = 1 - alpha
#pragma unroll
    for (int k = 0; k < KFRAG; ++k) {
        bool v = (fid[k] >= 0);
        zinv[k] = v ? ((ZFAR - zb_[k]) * ZSCALE) : 0.0f;
        zmax = fmaxf(zmax, zinv[k]);
        // sigmoid(-d/sigma) = 1/(1+exp(d/sigma)); masked -> 0
        prob[k] = v ? (1.0f / (1.0f + __expf(dd_[k] * SIGMA_INV))) : 0.0f;
        keep *= (1.0f - prob[k]);
    }

    // winner's prob / zinv via the same cascade (static indices after unroll)
    float pw = 0.f, zw = 0.f;
#pragma unroll
    for (int k = KFRAG - 1; k >= 0; --k)
        if (fid[k] >= 0) { pw = prob[k]; zw = zinv[k]; }

    float delta = fmaxf(__expf((EPS - zmax) * GAMMA_INV), EPS);
    float denom = delta;
    float r = 0.f, g = 0.f, b = 0.f;

    if (fidw >= 0) {
        float w = pw * __expf((zw - zmax) * GAMMA_INV); // zw==zmax -> exp(0)=1
        float tr = fmaf(wb0, fcv[0], fmaf(wb1, fcv[3], wb2 * fcv[6]));
        float tg = fmaf(wb0, fcv[1], fmaf(wb1, fcv[4], wb2 * fcv[7]));
        float tb = fmaf(wb0, fcv[2], fmaf(wb1, fcv[5], wb2 * fcv[8]));
        denom += w;
        r = fmaf(w, tr, r);
        g = fmaf(w, tg, g);
        b = fmaf(w, tb, b);
    }

    // ---- rare extra gate-passers (~0.8%/pixel): execz-skipped bodies ----
#pragma unroll
    for (int k = 0; k < KFRAG; ++k) {
        if ((fid[k] >= 0) && (k != kw) && (zinv[k] - zmax > ZCUT)) {
            float w = prob[k] * __expf((zinv[k] - zmax) * GAMMA_INV);
            const float* bp = bary + (size_t)p * (KFRAG * 3) + k * 3;
            float c0 = bp[0], c1 = bp[1], c2 = bp[2];
            const float* fc = face_colors + (size_t)fid[k] * 9;
            float e[9];
#pragma unroll
            for (int i = 0; i < 9; ++i) e[i] = fc[i];
            float tr = fmaf(c0, e[0], fmaf(c1, e[3], c2 * e[6]));
            float tg = fmaf(c0, e[1], fmaf(c1, e[4], c2 * e[7]));
            float tb = fmaf(c0, e[2], fmaf(c1, e[5], c2 * e[8]));
            denom += w;
            r = fmaf(w, tr, r);
            g = fmaf(w, tg, g);
            b = fmaf(w, tb, b);
        }
    }

    float inv = 1.0f / denom;
    fvec4 o;
    o.x = (r + delta) * inv; // background = (1,1,1): + delta*1/denom
    o.y = (g + delta) * inv;
    o.z = (b + delta) * inv;
    o.w = keep;
    __builtin_nontemporal_store(o, (fvec4*)out + p);
}

extern "C" void kernel_launch(void* const* d_in, const int* in_sizes, int n_in,
                              void* d_out, int out_size, void* d_ws, size_t ws_size,
                              hipStream_t stream) {
    const int*   p2f         = (const int*)d_in[0];
    const float* bary        = (const float*)d_in[1];
    const float* zbuf        = (const float*)d_in[2];
    const float* dists       = (const float*)d_in[3];
    const float* face_colors = (const float*)d_in[4];
    float* out = (float*)d_out;

    int NP = in_sizes[0] / KFRAG; // N*H*W pixels
    int block = 256;
    int grid = (NP + block - 1) / block;
    soft_shader_kernel<<<grid, block, 0, stream>>>(
        p2f, bary, zbuf, dists, face_colors, out, NP);
}